// Round 1
// baseline (234.911 us; speedup 1.0000x reference)
//
#include <hip/hip_runtime.h>
#include <hip/hip_bf16.h>
#include <math.h>
#include <stdint.h>

typedef __bf16 bf16_t;
typedef bf16_t bf16x8 __attribute__((ext_vector_type(8)));
typedef bf16_t bf16x4 __attribute__((ext_vector_type(4)));
typedef float f32x4 __attribute__((ext_vector_type(4)));

#define GLOBAL_AS __attribute__((address_space(1)))
#define LDS_AS __attribute__((address_space(3)))

__device__ __forceinline__ void gload_lds16(const void* g, void* l) {
    __builtin_amdgcn_global_load_lds((const GLOBAL_AS unsigned int*)g,
                                     (LDS_AS unsigned int*)l, 16, 0, 0);
}

__device__ __forceinline__ f32x4 mfma16(bf16x8 a, bf16x8 b, f32x4 c) {
    return __builtin_amdgcn_mfma_f32_16x16x32_bf16(a, b, c, 0, 0, 0);
}

// ---------------------------------------------------------------- LayerNorm
// one block per row of 1024; fp32 in, bf16 out
__global__ void ln_kernel(const float* __restrict__ x, const float* __restrict__ g,
                          const float* __restrict__ b, bf16_t* __restrict__ out)
{
    const int row = blockIdx.x;
    const int tid = threadIdx.x;
    const float4 v = ((const float4*)(x + (size_t)row * 1024))[tid];
    float s  = v.x + v.y + v.z + v.w;
    float s2 = v.x * v.x + v.y * v.y + v.z * v.z + v.w * v.w;
    #pragma unroll
    for (int m = 1; m < 64; m <<= 1) {
        s  += __shfl_xor(s, m);
        s2 += __shfl_xor(s2, m);
    }
    __shared__ float red[8];
    const int wid = tid >> 6, lane = tid & 63;
    if (lane == 0) { red[wid] = s; red[4 + wid] = s2; }
    __syncthreads();
    s  = red[0] + red[1] + red[2] + red[3];
    s2 = red[4] + red[5] + red[6] + red[7];
    const float mu  = s * (1.0f / 1024.0f);
    const float var = s2 * (1.0f / 1024.0f) - mu * mu;
    const float rs  = rsqrtf(var + 1e-5f);
    const float4 gv = ((const float4*)g)[tid];
    const float4 bv = ((const float4*)b)[tid];
    bf16x4 o;
    o[0] = (bf16_t)((v.x - mu) * rs * gv.x + bv.x);
    o[1] = (bf16_t)((v.y - mu) * rs * gv.y + bv.y);
    o[2] = (bf16_t)((v.z - mu) * rs * gv.z + bv.z);
    o[3] = (bf16_t)((v.w - mu) * rs * gv.w + bv.w);
    *(bf16x4*)&out[(size_t)row * 1024 + tid * 4] = o;
}

// ---------------------------------------------------------------- fp32 -> bf16
__global__ void cvt_bf16(const float* __restrict__ in, bf16_t* __restrict__ out, int n4)
{
    const int i = blockIdx.x * 256 + threadIdx.x;
    if (i < n4) {
        const float4 v = ((const float4*)in)[i];
        bf16x4 o;
        o[0] = (bf16_t)v.x; o[1] = (bf16_t)v.y; o[2] = (bf16_t)v.z; o[3] = (bf16_t)v.w;
        *(bf16x4*)&out[(size_t)i * 4] = o;
    }
}

// ---------------------------------------------------------------- RoPE tables
// cos/sin [1024 pos][64 dim] fp32
__global__ void rope_tables(float* __restrict__ cb, float* __restrict__ sb)
{
    const int p = blockIdx.x;   // 0..1023
    const int d = threadIdx.x;  // 0..63
    const int hh = p >> 5, ww = p & 31;
    const int idx = d & 15;
    const float invf = powf(10000.0f, -(float)idx / 16.0f);
    const float posv = (d >= 32) ? (float)hh : (float)ww;
    const float f = posv * invf;
    cb[p * 64 + d] = cosf(f);
    sb[p * 64 + d] = sinf(f);
}

// ---------------------------------------------------------------- RoPE apply (in-place, Q scaled by 1/8)
__global__ void rope_apply(bf16_t* __restrict__ Qb, bf16_t* __restrict__ Kb,
                           const float* __restrict__ cb, const float* __restrict__ sb)
{
    const int gid = blockIdx.x * 256 + threadIdx.x;   // 524288 total
    const int row = gid >> 2;                         // bh*1024 + pos
    const int d0  = (gid & 3) * 8;                    // 0,8,16,24  (always < 32)
    const int pos = row & 1023;
    const float4* cp = (const float4*)(cb + pos * 64);
    const float4* sp = (const float4*)(sb + pos * 64);
    const float4 c0 = cp[d0 / 4], c1 = cp[d0 / 4 + 1];
    const float4 C0 = cp[d0 / 4 + 8], C1 = cp[d0 / 4 + 9];
    const float4 s0 = sp[d0 / 4], s1 = sp[d0 / 4 + 1];
    const float4 S0 = sp[d0 / 4 + 8], S1 = sp[d0 / 4 + 9];
    const float cl[8] = {c0.x,c0.y,c0.z,c0.w,c1.x,c1.y,c1.z,c1.w};
    const float sl[8] = {s0.x,s0.y,s0.z,s0.w,s1.x,s1.y,s1.z,s1.w};
    const float ch[8] = {C0.x,C0.y,C0.z,C0.w,C1.x,C1.y,C1.z,C1.w};
    const float sh[8] = {S0.x,S0.y,S0.z,S0.w,S1.x,S1.y,S1.z,S1.w};
    const size_t base = (size_t)row * 64 + d0;
    bf16x8 qlo = *(bf16x8*)&Qb[base], qhi = *(bf16x8*)&Qb[base + 32];
    bf16x8 klo = *(bf16x8*)&Kb[base], khi = *(bf16x8*)&Kb[base + 32];
    bf16x8 oql, oqh, okl, okh;
    #pragma unroll
    for (int j = 0; j < 8; ++j) {
        const float ql = (float)qlo[j], qh = (float)qhi[j];
        oql[j] = (bf16_t)((ql * cl[j] - qh * sl[j]) * 0.125f);
        oqh[j] = (bf16_t)((qh * ch[j] + ql * sh[j]) * 0.125f);
        const float kl = (float)klo[j], kh = (float)khi[j];
        okl[j] = (bf16_t)(kl * cl[j] - kh * sl[j]);
        okh[j] = (bf16_t)(kh * ch[j] + kl * sh[j]);
    }
    *(bf16x8*)&Qb[base]      = oql;
    *(bf16x8*)&Qb[base + 32] = oqh;
    *(bf16x8*)&Kb[base]      = okl;
    *(bf16x8*)&Kb[base + 32] = okh;
}

// ---------------------------------------------------------------- V transpose: [bh][pos][64] -> [bh][64][1024]
__global__ void vtrans(const bf16_t* __restrict__ Vb, bf16_t* __restrict__ Vt)
{
    const int bh = blockIdx.y;
    const int pt = blockIdx.x;     // 16 tiles of 64 positions
    __shared__ bf16_t t[64 * 72];
    const int tid = threadIdx.x;
    const int r = tid >> 2, c = (tid & 3) * 16;
    const bf16_t* src = Vb + ((size_t)bh << 16) + (size_t)(pt * 64 + r) * 64 + c;
    *(bf16x8*)&t[r * 72 + c]     = *(const bf16x8*)src;
    *(bf16x8*)&t[r * 72 + c + 8] = *(const bf16x8*)(src + 8);
    __syncthreads();
    bf16x8 a, b2;
    #pragma unroll
    for (int i = 0; i < 8; ++i) a[i]  = t[(c + i) * 72 + r];
    #pragma unroll
    for (int i = 0; i < 8; ++i) b2[i] = t[(c + 8 + i) * 72 + r];
    bf16_t* dst = Vt + ((size_t)bh << 16) + (size_t)r * 1024 + pt * 64 + c;
    *(bf16x8*)dst       = a;
    *(bf16x8*)(dst + 8) = b2;
}

// ---------------------------------------------------------------- GEMM C = A(bf16,[M][K]) * B(bf16,[N][K])^T
// EPI 0: scatter bf16 into Q/K/V buffers.  EPI 1: fp32 to Cout.
template <int EPI>
__global__ __launch_bounds__(256, 2)
void gemm_bt(const bf16_t* __restrict__ A, const bf16_t* __restrict__ Bw,
             int M, int N, int K,
             bf16_t* __restrict__ Qb, bf16_t* __restrict__ Kb, bf16_t* __restrict__ Vb,
             float* __restrict__ Cout)
{
    __shared__ bf16_t Asm[128 * 64];
    __shared__ bf16_t Bsm[128 * 64];
    const int tid  = threadIdx.x;
    const int lane = tid & 63;
    const int wid  = tid >> 6;
    const int wr = wid >> 1, wc = wid & 1;
    const int bm = blockIdx.y * 128;
    const int bn = blockIdx.x * 128;

    f32x4 acc[4][4] = {};

    const int r0  = tid >> 3;
    const int ke0 = (tid & 7) * 8;

    for (int k0 = 0; k0 < K; k0 += 64) {
        __syncthreads();
        #pragma unroll
        for (int i = 0; i < 4; ++i) {
            gload_lds16(A  + (size_t)(bm + r0 + i * 32) * K + k0 + ke0, (char*)Asm + i * 4096 + tid * 16);
            gload_lds16(Bw + (size_t)(bn + r0 + i * 32) * K + k0 + ke0, (char*)Bsm + i * 4096 + tid * 16);
        }
        __syncthreads();
        #pragma unroll
        for (int kk = 0; kk < 2; ++kk) {
            bf16x8 af[4], bv[4];
            #pragma unroll
            for (int mi = 0; mi < 4; ++mi)
                af[mi] = *(const bf16x8*)&Asm[(wr * 64 + mi * 16 + (lane & 15)) * 64 + kk * 32 + (lane >> 4) * 8];
            #pragma unroll
            for (int nj = 0; nj < 4; ++nj)
                bv[nj] = *(const bf16x8*)&Bsm[(wc * 64 + nj * 16 + (lane & 15)) * 64 + kk * 32 + (lane >> 4) * 8];
            #pragma unroll
            for (int mi = 0; mi < 4; ++mi)
                #pragma unroll
                for (int nj = 0; nj < 4; ++nj)
                    acc[mi][nj] = mfma16(af[mi], bv[nj], acc[mi][nj]);
        }
    }

    #pragma unroll
    for (int mi = 0; mi < 4; ++mi) {
        #pragma unroll
        for (int nj = 0; nj < 4; ++nj) {
            #pragma unroll
            for (int r = 0; r < 4; ++r) {
                const int m = bm + wr * 64 + mi * 16 + (lane >> 4) * 4 + r;
                const int n = bn + wc * 64 + nj * 16 + (lane & 15);
                const float v = acc[mi][nj][r];
                if (EPI == 0) {
                    const int sel  = n >> 10;
                    const int head = (n >> 6) & 15;
                    const int d    = n & 63;
                    const int bfi  = m >> 10;
                    const int pos  = m & 1023;
                    const size_t idx = (((size_t)(bfi * 16 + head)) << 16) + (size_t)pos * 64 + d;
                    bf16_t* dst = (sel == 0) ? Qb : ((sel == 1) ? Kb : Vb);
                    dst[idx] = (bf16_t)v;
                } else {
                    Cout[(size_t)m * N + n] = v;
                }
            }
        }
    }
}

// ---------------------------------------------------------------- flash attention
// grid (8 q-tiles, 128 bh); block 256 = 4 waves x 32 q-rows; full S=1024 K iterated in 64-chunks
__global__ __launch_bounds__(256, 2)
void attn_kernel(const bf16_t* __restrict__ Q, const bf16_t* __restrict__ Kg,
                 const bf16_t* __restrict__ Vt, bf16_t* __restrict__ AO)
{
    const int bh  = blockIdx.y;
    const int qt  = blockIdx.x;
    const int tid = threadIdx.x;
    const int lane = tid & 63;
    const int wid  = tid >> 6;

    __shared__ bf16_t Ksm[64 * 72];
    __shared__ bf16_t Vsm[64 * 72];
    __shared__ bf16_t Psm[4][32 * 72];

    const size_t hb = (size_t)bh << 16;
    const bf16_t* Qp = Q  + hb;
    const bf16_t* Kp = Kg + hb;
    const bf16_t* Vp = Vt + hb;

    bf16x8 qf[2][2];
    #pragma unroll
    for (int qtl = 0; qtl < 2; ++qtl)
        #pragma unroll
        for (int kk = 0; kk < 2; ++kk)
            qf[qtl][kk] = *(const bf16x8*)&Qp[(size_t)(qt * 128 + wid * 32 + qtl * 16 + (lane & 15)) * 64
                                             + kk * 32 + (lane >> 4) * 8];

    f32x4 o[2][4] = {};
    float mrow[2][4], lrow[2][4];
    #pragma unroll
    for (int a = 0; a < 2; ++a)
        #pragma unroll
        for (int r = 0; r < 4; ++r) { mrow[a][r] = -INFINITY; lrow[a][r] = 0.0f; }

    const int sr = tid >> 2;
    const int sc = (tid & 3) * 16;

    for (int kt = 0; kt < 16; ++kt) {
        __syncthreads();
        {
            const bf16_t* ks = Kp + (size_t)(kt * 64 + sr) * 64 + sc;
            *(bf16x8*)&Ksm[sr * 72 + sc]     = *(const bf16x8*)ks;
            *(bf16x8*)&Ksm[sr * 72 + sc + 8] = *(const bf16x8*)(ks + 8);
            const bf16_t* vs = Vp + (size_t)sr * 1024 + kt * 64 + sc;
            *(bf16x8*)&Vsm[sr * 72 + sc]     = *(const bf16x8*)vs;
            *(bf16x8*)&Vsm[sr * 72 + sc + 8] = *(const bf16x8*)(vs + 8);
        }
        __syncthreads();

        f32x4 s[2][4] = {};
        #pragma unroll
        for (int kk = 0; kk < 2; ++kk) {
            bf16x8 kf[4];
            #pragma unroll
            for (int k4 = 0; k4 < 4; ++k4)
                kf[k4] = *(const bf16x8*)&Ksm[(k4 * 16 + (lane & 15)) * 72 + kk * 32 + (lane >> 4) * 8];
            #pragma unroll
            for (int qtl = 0; qtl < 2; ++qtl)
                #pragma unroll
                for (int k4 = 0; k4 < 4; ++k4)
                    s[qtl][k4] = mfma16(qf[qtl][kk], kf[k4], s[qtl][k4]);
        }

        #pragma unroll
        for (int qtl = 0; qtl < 2; ++qtl) {
            #pragma unroll
            for (int r = 0; r < 4; ++r) {
                float mx = fmaxf(fmaxf(s[qtl][0][r], s[qtl][1][r]), fmaxf(s[qtl][2][r], s[qtl][3][r]));
                mx = fmaxf(mx, __shfl_xor(mx, 1));
                mx = fmaxf(mx, __shfl_xor(mx, 2));
                mx = fmaxf(mx, __shfl_xor(mx, 4));
                mx = fmaxf(mx, __shfl_xor(mx, 8));
                const float mold = mrow[qtl][r];
                const float mnew = fmaxf(mold, mx);
                const float alpha = __expf(mold - mnew);
                float ps = 0.0f;
                #pragma unroll
                for (int k4 = 0; k4 < 4; ++k4) {
                    const float p = __expf(s[qtl][k4][r] - mnew);
                    s[qtl][k4][r] = p;
                    ps += p;
                }
                ps += __shfl_xor(ps, 1);
                ps += __shfl_xor(ps, 2);
                ps += __shfl_xor(ps, 4);
                ps += __shfl_xor(ps, 8);
                lrow[qtl][r] = lrow[qtl][r] * alpha + ps;
                mrow[qtl][r] = mnew;
                #pragma unroll
                for (int dt = 0; dt < 4; ++dt) o[qtl][dt][r] *= alpha;
            }
        }

        bf16_t* pw = &Psm[wid][0];
        #pragma unroll
        for (int qtl = 0; qtl < 2; ++qtl)
            #pragma unroll
            for (int k4 = 0; k4 < 4; ++k4)
                #pragma unroll
                for (int r = 0; r < 4; ++r)
                    pw[(qtl * 16 + (lane >> 4) * 4 + r) * 72 + k4 * 16 + (lane & 15)] = (bf16_t)s[qtl][k4][r];

        #pragma unroll
        for (int kk = 0; kk < 2; ++kk) {
            bf16x8 pf[2], vf[4];
            #pragma unroll
            for (int qtl = 0; qtl < 2; ++qtl)
                pf[qtl] = *(const bf16x8*)&pw[(qtl * 16 + (lane & 15)) * 72 + kk * 32 + (lane >> 4) * 8];
            #pragma unroll
            for (int dt = 0; dt < 4; ++dt)
                vf[dt] = *(const bf16x8*)&Vsm[(dt * 16 + (lane & 15)) * 72 + kk * 32 + (lane >> 4) * 8];
            #pragma unroll
            for (int qtl = 0; qtl < 2; ++qtl)
                #pragma unroll
                for (int dt = 0; dt < 4; ++dt)
                    o[qtl][dt] = mfma16(pf[qtl], vf[dt], o[qtl][dt]);
        }
    }

    const int bfi = bh >> 4;
    const int hh  = bh & 15;
    #pragma unroll
    for (int qtl = 0; qtl < 2; ++qtl) {
        #pragma unroll
        for (int r = 0; r < 4; ++r) {
            const float inv = 1.0f / lrow[qtl][r];
            const int qrow = qt * 128 + wid * 32 + qtl * 16 + (lane >> 4) * 4 + r;
            const size_t mbase = (size_t)(bfi * 1024 + qrow) * 1024 + hh * 64;
            #pragma unroll
            for (int dt = 0; dt < 4; ++dt)
                AO[mbase + dt * 16 + (lane & 15)] = (bf16_t)(o[qtl][dt][r] * inv);
        }
    }
}

// ----------------------------------------------------------------
extern "C" void kernel_launch(void* const* d_in, const int* in_sizes, int n_in,
                              void* d_out, int out_size, void* d_ws, size_t ws_size,
                              hipStream_t stream)
{
    const float* x     = (const float*)d_in[0];
    const float* w_qkv = (const float*)d_in[1];
    const float* w_out = (const float*)d_in[2];
    const float* ln_g  = (const float*)d_in[3];
    const float* ln_b  = (const float*)d_in[4];

    char* ws = (char*)d_ws;
    // layout (MB offsets): xn 0..16, Q 16..32, K 32..48, V/AO 48..64, Vt 64..80,
    // wq_bf 80..86, wo_bf 87..89, cos 90, sin 91  (total ~92 MB)
    bf16_t* xn  = (bf16_t*)(ws);
    bf16_t* Qb  = (bf16_t*)(ws + ((size_t)16 << 20));
    bf16_t* Kb  = (bf16_t*)(ws + ((size_t)32 << 20));
    bf16_t* Vb  = (bf16_t*)(ws + ((size_t)48 << 20));   // reused as AO after vtrans
    bf16_t* Vt  = (bf16_t*)(ws + ((size_t)64 << 20));
    bf16_t* wqb = (bf16_t*)(ws + ((size_t)80 << 20));
    bf16_t* wob = (bf16_t*)(ws + ((size_t)87 << 20));
    float*  cb  = (float*)(ws + ((size_t)90 << 20));
    float*  sb  = (float*)(ws + ((size_t)91 << 20));
    bf16_t* AO  = Vb;

    cvt_bf16<<<dim3(3072), dim3(256), 0, stream>>>(w_qkv, wqb, 786432);
    cvt_bf16<<<dim3(1024), dim3(256), 0, stream>>>(w_out, wob, 262144);
    rope_tables<<<dim3(1024), dim3(64), 0, stream>>>(cb, sb);
    ln_kernel<<<dim3(8192), dim3(256), 0, stream>>>(x, ln_g, ln_b, xn);
    gemm_bt<0><<<dim3(24, 64), dim3(256), 0, stream>>>(xn, wqb, 8192, 3072, 1024, Qb, Kb, Vb, nullptr);
    vtrans<<<dim3(16, 128), dim3(256), 0, stream>>>(Vb, Vt);
    rope_apply<<<dim3(2048), dim3(256), 0, stream>>>(Qb, Kb, cb, sb);
    attn_kernel<<<dim3(8, 128), dim3(256), 0, stream>>>(Qb, Kb, Vt, AO);
    gemm_bt<1><<<dim3(8, 64), dim3(256), 0, stream>>>(AO, wob, 8192, 1024, 1024, nullptr, nullptr, nullptr, (float*)d_out);

    (void)in_sizes; (void)n_in; (void)out_size; (void)ws_size;
}